// Round 3
// 1080.614 us; speedup vs baseline: 2.5778x; 2.5778x over previous
//
#include <hip/hip_runtime.h>
#include <hip/hip_bf16.h>

#define M_ROWS 16384
#define K_IN   2048
#define N_OUT  8192
#define OG     12            // outputs per structural group (identical k-list within group)
#define NG     683           // ceil(8192/12)
#define KUMAX  64            // capacity of per-group k-list (actual ~32 after o=0 exclusion)
#define GPB    4             // groups per main block
#define OTW    (OG*GPB)      // 48 output cols per block = 3 full 64B lines
#define NTO    171           // ceil(683/4)
#define MT     256           // m rows per main block
#define MAXOFF ((K_IN - 1) * (M_ROWS * 2))   // largest valid xT byte offset (row start)

// ---------------- transpose: x[M][K] f32 -> xT[K][M] bf16 (unchanged, verified) ----------------
__global__ void ninja_xpose(const float* __restrict__ x, __hip_bfloat16* __restrict__ xT) {
    __shared__ float tile[64][65];
    int mt = blockIdx.x, kt = blockIdx.y;
    int t = threadIdx.x;
    int c = t & 63;
    int r4 = t >> 6;
#pragma unroll
    for (int i = 0; i < 16; i++) {
        int r = r4 + i * 4;
        tile[r][c] = x[(size_t)(mt * 64 + r) * K_IN + kt * 64 + c];
    }
    __syncthreads();
#pragma unroll
    for (int i = 0; i < 16; i++) {
        int r = r4 + i * 4;
        xT[(size_t)(kt * 64 + r) * M_ROWS + mt * 64 + c] = __float2bfloat16(tile[c][r]);
    }
}

// ---------------- prep: per-group k-list (byte offsets) + dense weight panel ----------------
// Output 0 (the only dense output) is EXCLUDED here; its column is produced by ninja_gemv0.
__global__ void ninja_prep(const float* __restrict__ mask, const float* __restrict__ W,
                           int* __restrict__ koff, int* __restrict__ kuArr,
                           float* __restrict__ Wd) {
    int g = blockIdx.x, t = threadIdx.x;
    int o0 = g * OG;
    int no = min(OG, N_OUT - o0);
    __shared__ int cnt;
    __shared__ int kl[KUMAX];
    if (t == 0) cnt = 0;
    __syncthreads();
    for (int k = t; k < K_IN; k += 256) {
        int any = 0;
        for (int oo = 0; oo < no; oo++) {
            int o = o0 + oo;
            any |= (o != 0) & (mask[(size_t)o * K_IN + k] != 0.0f);
        }
        if (any) {
            int p = atomicAdd(&cnt, 1);
            if (p < KUMAX) kl[p] = k;
        }
    }
    __syncthreads();
    int c = cnt;
    if (c > KUMAX) {                  // never expected for this mask; cold safety path
        if (t == 0) kuArr[g] = -1;
        return;
    }
    int kup = (c + 3) & ~3;
    for (int j = c + t; j < kup; j += 256) kl[j] = 0;   // pad entries: k=0, zero weight
    __syncthreads();
    if (t == 0) kuArr[g] = kup;
    for (int j = t; j < KUMAX; j += 256)
        koff[g * KUMAX + j] = (j < kup) ? kl[j] * (M_ROWS * 2) : 0;   // byte offset into xT
    for (int idx = t; idx < KUMAX * OG; idx += 256) {   // 768 floats, 3 iters
        int jk = idx / OG, oo = idx - jk * OG;
        float v = 0.0f;
        int o = o0 + oo;
        if (jk < c && oo < no && o != 0) {
            size_t p = (size_t)o * K_IN + kl[jk];
            v = mask[p] * W[p];
        }
        Wd[(size_t)g * (KUMAX * OG) + idx] = v;
    }
}

// ---------------- main: block = 256 m rows x 4 groups (48 output cols) ----------------
__global__ __launch_bounds__(256)
void ninja_main(const __hip_bfloat16* __restrict__ xT,
                const float* __restrict__ mask, const float* __restrict__ W,
                const float* __restrict__ bias,
                const int* __restrict__ koff, const int* __restrict__ kuArr,
                const float* __restrict__ Wd, float* __restrict__ y) {
    __shared__ __align__(16) float wpanS[GPB][KUMAX][OG];   // 12 KB
    __shared__ int   koffS[GPB][KUMAX];                     // 1 KB
    __shared__ int   kusS[GPB];
    __shared__ float biasS[OTW];
    __shared__ __align__(16) float ytile[64][OTW];          // 12 KB

    int t = threadIdx.x;
    int og0 = blockIdx.x * GPB;
    int o0  = og0 * OG;

    { // stage k-offset lists (coalesced), defensively clamped to valid xT range
        int g = t >> 6, j = t & 63;
        int gg = og0 + g;
        int v = (gg < NG) ? koff[gg * KUMAX + j] : 0;
        koffS[g][j] = min(max(v, 0), MAXOFF);
    }
    if (t < GPB) kusS[t] = (og0 + t < NG) ? kuArr[og0 + t] : 0;
    if (t < OTW) biasS[t] = (o0 + t < N_OUT) ? bias[o0 + t] : 0.0f;
    // stage weight panels as float4 (768 float4 total, 3 per thread)
#pragma unroll
    for (int i = 0; i < 3; i++) {
        int f = t + i * 256;                 // global float4 index 0..767
        int g = f / 192, r = f - g * 192;    // group, within-group float4 index
        int gg = og0 + g;
        float4 v = make_float4(0.f, 0.f, 0.f, 0.f);
        if (gg < NG) v = reinterpret_cast<const float4*>(Wd + (size_t)gg * (KUMAX * OG))[r];
        reinterpret_cast<float4*>(&wpanS[0][0][0])[f] = v;   // linear index over whole panel
    }
    __syncthreads();

    int m = blockIdx.y * MT + t;
    const char* xb = reinterpret_cast<const char*>(xT + m);

    float acc[GPB][OG];
#pragma unroll
    for (int g = 0; g < GPB; g++)
#pragma unroll
        for (int oo = 0; oo < OG; oo++) acc[g][oo] = 0.0f;

#pragma unroll
    for (int g = 0; g < GPB; g++) {
        int ku = min(kusS[g], KUMAX);
        if (ku >= 0) {
            for (int jk = 0; jk < ku; jk += 4) {     // ku is padded to a multiple of 4
#pragma unroll
                for (int u = 0; u < 4; u++) {
                    int off = koffS[g][jk + u];      // uniform ds_read (broadcast)
                    float xv = __bfloat162float(
                        *reinterpret_cast<const __hip_bfloat16*>(xb + off));
                    const float* w = &wpanS[g][jk + u][0];
                    float4 w0 = *reinterpret_cast<const float4*>(w);
                    float4 w1 = *reinterpret_cast<const float4*>(w + 4);
                    float4 w2 = *reinterpret_cast<const float4*>(w + 8);
                    acc[g][0]  = fmaf(xv, w0.x, acc[g][0]);
                    acc[g][1]  = fmaf(xv, w0.y, acc[g][1]);
                    acc[g][2]  = fmaf(xv, w0.z, acc[g][2]);
                    acc[g][3]  = fmaf(xv, w0.w, acc[g][3]);
                    acc[g][4]  = fmaf(xv, w1.x, acc[g][4]);
                    acc[g][5]  = fmaf(xv, w1.y, acc[g][5]);
                    acc[g][6]  = fmaf(xv, w1.z, acc[g][6]);
                    acc[g][7]  = fmaf(xv, w1.w, acc[g][7]);
                    acc[g][8]  = fmaf(xv, w2.x, acc[g][8]);
                    acc[g][9]  = fmaf(xv, w2.y, acc[g][9]);
                    acc[g][10] = fmaf(xv, w2.z, acc[g][10]);
                    acc[g][11] = fmaf(xv, w2.w, acc[g][11]);
                }
            }
        } else {
            // cold dense safety path (list overflow — not expected for this mask)
            int gg = og0 + g, go0 = gg * OG;
            int no = min(OG, N_OUT - go0);
            for (int k = 0; k < K_IN; k++) {
                float xv = __bfloat162float(
                    *reinterpret_cast<const __hip_bfloat16*>(xb + k * (M_ROWS * 2)));
#pragma unroll
                for (int oo = 0; oo < OG; oo++) {
                    float wv = 0.f;
                    if (oo < no) {
                        size_t p = (size_t)(go0 + oo) * K_IN + k;
                        wv = mask[p] * W[p];
                    }
                    acc[g][oo] = fmaf(xv, wv, acc[g][oo]);
                }
            }
        }
    }

    // ---- coalesced full-line store via LDS transpose, 4 chunks of 64 m-rows ----
    int WID = min(OTW, N_OUT - o0);        // 48 normally, 32 for the last o-tile
    int mbase = blockIdx.y * MT;
#pragma unroll
    for (int cch = 0; cch < 4; cch++) {
        if ((t >> 6) == cch) {             // producing wave: dump acc(+bias) for its 64 rows
            int r = t & 63;
#pragma unroll
            for (int g = 0; g < GPB; g++)
#pragma unroll
                for (int oo = 0; oo < OG; oo++)
                    ytile[r][g * OG + oo] = acc[g][oo] + biasS[g * OG + oo];
        }
        __syncthreads();
        float4* yb = reinterpret_cast<float4*>(y + (size_t)(mbase + cch * 64) * N_OUT + o0);
        if (WID == 48) {
#pragma unroll
            for (int i = 0; i < 3; i++) {
                int idx = t + i * 256;
                int r = idx / 12, q = idx - r * 12;
                float4 v = *reinterpret_cast<const float4*>(&ytile[r][4 * q]);
                yb[(size_t)r * (N_OUT / 4) + q] = v;
            }
        } else {                            // WID == 32
#pragma unroll
            for (int i = 0; i < 2; i++) {
                int idx = t + i * 256;
                int r = idx >> 3, q = idx & 7;
                float4 v = *reinterpret_cast<const float4*>(&ytile[r][4 * q]);
                yb[(size_t)r * (N_OUT / 4) + q] = v;
            }
        }
        __syncthreads();
    }
}

// ---------------- gemv0: dense output column o=0, no atomics ----------------
// Block handles 64 m rows; 4 waves each cover a 512-wide k-slice; LDS reduce; overwrite y[m][0].
__global__ __launch_bounds__(256)
void ninja_gemv0(const __hip_bfloat16* __restrict__ xT,
                 const float* __restrict__ mask, const float* __restrict__ W,
                 const float* __restrict__ bias, float* __restrict__ y) {
    __shared__ float w0[K_IN];      // 8 KB
    __shared__ float part[4][64];
    int t = threadIdx.x;
    for (int k = t; k < K_IN; k += 256) w0[k] = mask[k] * W[k];   // mask row 0 = output 0
    __syncthreads();
    int ml = t & 63;
    int kq = t >> 6;                // wave-uniform k-slice id
    int m  = blockIdx.x * 64 + ml;
    const __hip_bfloat16* xp = xT + (size_t)(kq * 512) * M_ROWS + m;
    float a = 0.f;
    for (int k = 0; k < 512; k += 8) {
#pragma unroll
        for (int u = 0; u < 8; u++)
            a = fmaf(w0[kq * 512 + k + u],
                     __bfloat162float(xp[(size_t)(k + u) * M_ROWS]), a);
    }
    part[kq][ml] = a;
    __syncthreads();
    if (t < 64) {
        float s = part[0][t] + part[1][t] + part[2][t] + part[3][t];
        y[(size_t)(blockIdx.x * 64 + t) * N_OUT] = s + bias[0];
    }
}

// ---------------- fallback: plain tiled dense GEMM (used only if ws too small) ----------------
__global__ void ninja_fallback(const float* __restrict__ x, const float* __restrict__ W,
                               const float* __restrict__ bias, const float* __restrict__ mask,
                               float* __restrict__ y) {
    int ot = blockIdx.x, mtile = blockIdx.y, t = threadIdx.x;
    int mloc = t & 63;
    int q = t >> 6;
    int m = mtile * 64 + mloc;
    int obase = ot * 64 + q * 16;
    float acc[16];
#pragma unroll
    for (int i = 0; i < 16; i++) acc[i] = 0.0f;
    __shared__ float xs[32][65];
    for (int kt = 0; kt < K_IN; kt += 32) {
#pragma unroll
        for (int j = 0; j < 8; j++) {
            int idx = t + j * 256;
            int r = idx >> 5, cc = idx & 31;
            xs[cc][r] = x[(size_t)(mtile * 64 + r) * K_IN + kt + cc];
        }
        __syncthreads();
        for (int kk = 0; kk < 32; kk++) {
            float xv = xs[kk][mloc];
#pragma unroll
            for (int i = 0; i < 16; i++) {
                size_t p = (size_t)(obase + i) * K_IN + kt + kk;
                acc[i] = fmaf(xv, mask[p] * W[p], acc[i]);
            }
        }
        __syncthreads();
    }
#pragma unroll
    for (int i = 0; i < 16; i++) acc[i] += bias[obase + i];
    float4* yp = reinterpret_cast<float4*>(y + (size_t)m * N_OUT + obase);
#pragma unroll
    for (int i = 0; i < 4; i++)
        yp[i] = make_float4(acc[4 * i], acc[4 * i + 1], acc[4 * i + 2], acc[4 * i + 3]);
}

extern "C" void kernel_launch(void* const* d_in, const int* in_sizes, int n_in,
                              void* d_out, int out_size, void* d_ws, size_t ws_size,
                              hipStream_t stream) {
    const float* x    = (const float*)d_in[0];
    const float* W    = (const float*)d_in[1];
    const float* bias = (const float*)d_in[2];
    const float* mask = (const float*)d_in[3];
    float* y = (float*)d_out;

    size_t xT_bytes    = (size_t)K_IN * M_ROWS * sizeof(__hip_bfloat16);    // 64 MB
    size_t koff_off    = xT_bytes;
    size_t koff_bytes  = (size_t)NG * KUMAX * sizeof(int);
    size_t ku_off      = koff_off + ((koff_bytes + 255) & ~(size_t)255);
    size_t ku_bytes    = ((size_t)NG * sizeof(int) + 255) & ~(size_t)255;
    size_t wd_off      = ku_off + ku_bytes;
    size_t wd_bytes    = (size_t)NG * KUMAX * OG * sizeof(float);           // ~2.1 MB
    size_t needed      = wd_off + wd_bytes;

    if (ws_size < needed) {
        ninja_fallback<<<dim3(N_OUT / 64, M_ROWS / 64), 256, 0, stream>>>(x, W, bias, mask, y);
        return;
    }

    char* ws = (char*)d_ws;
    __hip_bfloat16* xT = (__hip_bfloat16*)ws;
    int*   koff  = (int*)(ws + koff_off);
    int*   kuArr = (int*)(ws + ku_off);
    float* Wd    = (float*)(ws + wd_off);

    ninja_xpose<<<dim3(M_ROWS / 64, K_IN / 64), 256, 0, stream>>>(x, xT);
    ninja_prep<<<dim3(NG), 256, 0, stream>>>(mask, W, koff, kuArr, Wd);
    ninja_main<<<dim3(NTO, M_ROWS / MT), 256, 0, stream>>>(xT, mask, W, bias, koff, kuArr, Wd, y);
    ninja_gemv0<<<dim3(M_ROWS / 64), 256, 0, stream>>>(xT, mask, W, bias, y);
}

// Round 4
// 887.861 us; speedup vs baseline: 3.1375x; 1.2171x over previous
//
#include <hip/hip_runtime.h>
#include <hip/hip_bf16.h>

#define M_ROWS 16384
#define K_IN   2048
#define N_OUT  8192
#define OG     12            // outputs per structural group (identical k-list within group)
#define NG     683           // ceil(8192/12)
#define KUMAX  64            // capacity of per-group k-list (actual ~32 after o=0 exclusion)
#define GPB    4             // groups per main block
#define OTW    (OG*GPB)      // 48 output cols per block = 3 full 64B lines
#define YPAD   52            // ytile row stride: 13 float4 (odd) -> conflict-free b128
#define NTO    171           // ceil(683/4)
#define MT     256           // m rows per main block
#define MAXOFF ((K_IN - 1) * (M_ROWS * 2))   // largest valid xT byte offset (row start)

// ---------------- transpose: x[M][K] f32 -> xT[K][M] bf16 (unchanged, verified) ----------------
__global__ void ninja_xpose(const float* __restrict__ x, __hip_bfloat16* __restrict__ xT) {
    __shared__ float tile[64][65];
    int mt = blockIdx.x, kt = blockIdx.y;
    int t = threadIdx.x;
    int c = t & 63;
    int r4 = t >> 6;
#pragma unroll
    for (int i = 0; i < 16; i++) {
        int r = r4 + i * 4;
        tile[r][c] = x[(size_t)(mt * 64 + r) * K_IN + kt * 64 + c];
    }
    __syncthreads();
#pragma unroll
    for (int i = 0; i < 16; i++) {
        int r = r4 + i * 4;
        xT[(size_t)(kt * 64 + r) * M_ROWS + mt * 64 + c] = __float2bfloat16(tile[c][r]);
    }
}

// ---------------- prep: per-group k-list (byte offsets) + dense weight panel ----------------
// Output 0 (the only dense output) is EXCLUDED here; its column is produced by ninja_gemv0.
__global__ void ninja_prep(const float* __restrict__ mask, const float* __restrict__ W,
                           int* __restrict__ koff, int* __restrict__ kuArr,
                           float* __restrict__ Wd) {
    int g = blockIdx.x, t = threadIdx.x;
    int o0 = g * OG;
    int no = min(OG, N_OUT - o0);
    __shared__ int cnt;
    __shared__ int kl[KUMAX];
    if (t == 0) cnt = 0;
    __syncthreads();
    for (int k = t; k < K_IN; k += 256) {
        int any = 0;
        for (int oo = 0; oo < no; oo++) {
            int o = o0 + oo;
            any |= (o != 0) & (mask[(size_t)o * K_IN + k] != 0.0f);
        }
        if (any) {
            int p = atomicAdd(&cnt, 1);
            if (p < KUMAX) kl[p] = k;
        }
    }
    __syncthreads();
    int c = cnt;
    if (c > KUMAX) {                  // never expected for this mask; cold safety path
        if (t == 0) kuArr[g] = -1;
        return;
    }
    int kup = (c + 3) & ~3;
    for (int j = c + t; j < kup; j += 256) kl[j] = 0;   // pad entries: k=0, zero weight
    __syncthreads();
    if (t == 0) kuArr[g] = kup;
    for (int j = t; j < KUMAX; j += 256)
        koff[g * KUMAX + j] = (j < kup) ? kl[j] * (M_ROWS * 2) : 0;   // byte offset into xT
    for (int idx = t; idx < KUMAX * OG; idx += 256) {   // 768 floats, 3 iters
        int jk = idx / OG, oo = idx - jk * OG;
        float v = 0.0f;
        int o = o0 + oo;
        if (jk < c && oo < no && o != 0) {
            size_t p = (size_t)o * K_IN + kl[jk];
            v = mask[p] * W[p];
        }
        Wd[(size_t)g * (KUMAX * OG) + idx] = v;
    }
}

// ---------------- main: block = 256 m rows x 4 groups (48 output cols) ----------------
// Weights are wave-uniform -> read via uniform float4 loads from global (s_load/K$),
// NOT via LDS (round-3 was LDS-broadcast-throughput-bound: 3x ds_read_b128 per jk).
__global__ __launch_bounds__(256)
void ninja_main(const __hip_bfloat16* __restrict__ xT,
                const float* __restrict__ mask, const float* __restrict__ W,
                const float* __restrict__ bias,
                const int* __restrict__ koff, const int* __restrict__ kuArr,
                const float* __restrict__ Wd, float* __restrict__ y) {
    __shared__ __align__(16) int koffS[GPB][KUMAX];         // 1 KB
    __shared__ int   kusS[GPB];
    __shared__ float biasS[OTW];
    __shared__ __align__(16) float ytile[64][YPAD];         // 13 KB, stride 13 f4 (odd)

    int t = threadIdx.x;
    int og0 = blockIdx.x * GPB;
    int o0  = og0 * OG;

    { // stage k-offset lists (coalesced), defensively clamped to valid xT range
        int g = t >> 6, j = t & 63;
        int gg = og0 + g;
        int v = (gg < NG) ? koff[gg * KUMAX + j] : 0;
        koffS[g][j] = min(max(v, 0), MAXOFF);
    }
    if (t < GPB) kusS[t] = (og0 + t < NG) ? kuArr[og0 + t] : 0;
    if (t < OTW) biasS[t] = (o0 + t < N_OUT) ? bias[o0 + t] : 0.0f;
    __syncthreads();

    int m = blockIdx.y * MT + t;
    const char* xb = reinterpret_cast<const char*>(xT + m);

    float acc[GPB][OG];
#pragma unroll
    for (int g = 0; g < GPB; g++)
#pragma unroll
        for (int oo = 0; oo < OG; oo++) acc[g][oo] = 0.0f;

#pragma unroll
    for (int g = 0; g < GPB; g++) {
        int gg = og0 + g;
        int ku = min(kusS[g], KUMAX);
        // block-uniform panel base -> uniform indices below -> scalar loads
        const float4* wp = reinterpret_cast<const float4*>(Wd + (size_t)min(gg, NG - 1) * (KUMAX * OG));
        if (ku >= 0) {
            for (int jk = 0; jk < ku; jk += 4) {     // ku is padded to a multiple of 4
                int4 ko = *reinterpret_cast<const int4*>(&koffS[g][jk]);  // uniform b128
#pragma unroll
                for (int u = 0; u < 4; u++) {
                    int off = (u == 0) ? ko.x : (u == 1) ? ko.y : (u == 2) ? ko.z : ko.w;
                    float xv = __bfloat162float(
                        *reinterpret_cast<const __hip_bfloat16*>(xb + off));
                    float4 w0 = wp[(jk + u) * 3 + 0];   // uniform -> s_load_dwordx4
                    float4 w1 = wp[(jk + u) * 3 + 1];
                    float4 w2 = wp[(jk + u) * 3 + 2];
                    acc[g][0]  = fmaf(xv, w0.x, acc[g][0]);
                    acc[g][1]  = fmaf(xv, w0.y, acc[g][1]);
                    acc[g][2]  = fmaf(xv, w0.z, acc[g][2]);
                    acc[g][3]  = fmaf(xv, w0.w, acc[g][3]);
                    acc[g][4]  = fmaf(xv, w1.x, acc[g][4]);
                    acc[g][5]  = fmaf(xv, w1.y, acc[g][5]);
                    acc[g][6]  = fmaf(xv, w1.z, acc[g][6]);
                    acc[g][7]  = fmaf(xv, w1.w, acc[g][7]);
                    acc[g][8]  = fmaf(xv, w2.x, acc[g][8]);
                    acc[g][9]  = fmaf(xv, w2.y, acc[g][9]);
                    acc[g][10] = fmaf(xv, w2.z, acc[g][10]);
                    acc[g][11] = fmaf(xv, w2.w, acc[g][11]);
                }
            }
        } else {
            // cold dense safety path (list overflow — not expected for this mask)
            int go0 = gg * OG;
            int no = min(OG, N_OUT - go0);
            for (int k = 0; k < K_IN; k++) {
                float xv = __bfloat162float(
                    *reinterpret_cast<const __hip_bfloat16*>(xb + k * (M_ROWS * 2)));
#pragma unroll
                for (int oo = 0; oo < OG; oo++) {
                    float wv = 0.f;
                    if (oo < no) {
                        size_t p = (size_t)(go0 + oo) * K_IN + k;
                        wv = mask[p] * W[p];
                    }
                    acc[g][oo] = fmaf(xv, wv, acc[g][oo]);
                }
            }
        }
    }

    // ---- coalesced full-line store via LDS transpose, 4 chunks of 64 m-rows ----
    int WID = min(OTW, N_OUT - o0);        // 48 normally, 32 for the last o-tile
    int mbase = blockIdx.y * MT;
#pragma unroll
    for (int cch = 0; cch < 4; cch++) {
        if ((t >> 6) == cch) {             // producing wave: dump acc(+bias) for its 64 rows
            int r = t & 63;
#pragma unroll
            for (int g = 0; g < GPB; g++)
#pragma unroll
                for (int oo = 0; oo < OG; oo++)
                    ytile[r][g * OG + oo] = acc[g][oo] + biasS[g * OG + oo];
        }
        __syncthreads();
        float4* yb = reinterpret_cast<float4*>(y + (size_t)(mbase + cch * 64) * N_OUT + o0);
        if (WID == 48) {
#pragma unroll
            for (int i = 0; i < 3; i++) {
                int idx = t + i * 256;
                int r = idx / 12, q = idx - r * 12;
                float4 v = *reinterpret_cast<const float4*>(&ytile[r][4 * q]);
                yb[(size_t)r * (N_OUT / 4) + q] = v;
            }
        } else {                            // WID == 32
#pragma unroll
            for (int i = 0; i < 2; i++) {
                int idx = t + i * 256;
                int r = idx >> 3, q = idx & 7;
                float4 v = *reinterpret_cast<const float4*>(&ytile[r][4 * q]);
                yb[(size_t)r * (N_OUT / 4) + q] = v;
            }
        }
        __syncthreads();
    }
}

// ---------------- gemv0: dense output column o=0, no atomics ----------------
// Block handles 64 m rows; 8 waves each cover a 256-wide k-slice; LDS reduce; overwrite y[m][0].
__global__ __launch_bounds__(512)
void ninja_gemv0(const __hip_bfloat16* __restrict__ xT,
                 const float* __restrict__ mask, const float* __restrict__ W,
                 const float* __restrict__ bias, float* __restrict__ y) {
    __shared__ float w0[K_IN];      // 8 KB
    __shared__ float part[8][64];
    int t = threadIdx.x;
    for (int k = t; k < K_IN; k += 512) w0[k] = mask[k] * W[k];   // mask row 0 = output 0
    __syncthreads();
    int ml = t & 63;
    int kq = t >> 6;                // wave-uniform k-slice id 0..7
    int m  = blockIdx.x * 64 + ml;
    const __hip_bfloat16* xp = xT + (size_t)(kq * 256) * M_ROWS + m;
    float a = 0.f;
    for (int k = 0; k < 256; k += 8) {
#pragma unroll
        for (int u = 0; u < 8; u++)
            a = fmaf(w0[kq * 256 + k + u],
                     __bfloat162float(xp[(size_t)(k + u) * M_ROWS]), a);
    }
    part[kq][ml] = a;
    __syncthreads();
    if (t < 64) {
        float s = ((part[0][t] + part[1][t]) + (part[2][t] + part[3][t]))
                + ((part[4][t] + part[5][t]) + (part[6][t] + part[7][t]));
        y[(size_t)(blockIdx.x * 64 + t) * N_OUT] = s + bias[0];
    }
}

// ---------------- fallback: plain tiled dense GEMM (used only if ws too small) ----------------
__global__ void ninja_fallback(const float* __restrict__ x, const float* __restrict__ W,
                               const float* __restrict__ bias, const float* __restrict__ mask,
                               float* __restrict__ y) {
    int ot = blockIdx.x, mtile = blockIdx.y, t = threadIdx.x;
    int mloc = t & 63;
    int q = t >> 6;
    int m = mtile * 64 + mloc;
    int obase = ot * 64 + q * 16;
    float acc[16];
#pragma unroll
    for (int i = 0; i < 16; i++) acc[i] = 0.0f;
    __shared__ float xs[32][65];
    for (int kt = 0; kt < K_IN; kt += 32) {
#pragma unroll
        for (int j = 0; j < 8; j++) {
            int idx = t + j * 256;
            int r = idx >> 5, cc = idx & 31;
            xs[cc][r] = x[(size_t)(mtile * 64 + r) * K_IN + kt + cc];
        }
        __syncthreads();
        for (int kk = 0; kk < 32; kk++) {
            float xv = xs[kk][mloc];
#pragma unroll
            for (int i = 0; i < 16; i++) {
                size_t p = (size_t)(obase + i) * K_IN + kt + kk;
                acc[i] = fmaf(xv, mask[p] * W[p], acc[i]);
            }
        }
        __syncthreads();
    }
#pragma unroll
    for (int i = 0; i < 16; i++) acc[i] += bias[obase + i];
    float4* yp = reinterpret_cast<float4*>(y + (size_t)m * N_OUT + obase);
#pragma unroll
    for (int i = 0; i < 4; i++)
        yp[i] = make_float4(acc[4 * i], acc[4 * i + 1], acc[4 * i + 2], acc[4 * i + 3]);
}

extern "C" void kernel_launch(void* const* d_in, const int* in_sizes, int n_in,
                              void* d_out, int out_size, void* d_ws, size_t ws_size,
                              hipStream_t stream) {
    const float* x    = (const float*)d_in[0];
    const float* W    = (const float*)d_in[1];
    const float* bias = (const float*)d_in[2];
    const float* mask = (const float*)d_in[3];
    float* y = (float*)d_out;

    size_t xT_bytes    = (size_t)K_IN * M_ROWS * sizeof(__hip_bfloat16);    // 64 MB
    size_t koff_off    = xT_bytes;
    size_t koff_bytes  = (size_t)NG * KUMAX * sizeof(int);
    size_t ku_off      = koff_off + ((koff_bytes + 255) & ~(size_t)255);
    size_t ku_bytes    = ((size_t)NG * sizeof(int) + 255) & ~(size_t)255;
    size_t wd_off      = ku_off + ku_bytes;
    size_t wd_bytes    = (size_t)NG * KUMAX * OG * sizeof(float);           // ~2.1 MB
    size_t needed      = wd_off + wd_bytes;

    if (ws_size < needed) {
        ninja_fallback<<<dim3(N_OUT / 64, M_ROWS / 64), 256, 0, stream>>>(x, W, bias, mask, y);
        return;
    }

    char* ws = (char*)d_ws;
    __hip_bfloat16* xT = (__hip_bfloat16*)ws;
    int*   koff  = (int*)(ws + koff_off);
    int*   kuArr = (int*)(ws + ku_off);
    float* Wd    = (float*)(ws + wd_off);

    ninja_xpose<<<dim3(M_ROWS / 64, K_IN / 64), 256, 0, stream>>>(x, xT);
    ninja_prep<<<dim3(NG), 256, 0, stream>>>(mask, W, koff, kuArr, Wd);
    ninja_main<<<dim3(NTO, M_ROWS / MT), 256, 0, stream>>>(xT, mask, W, bias, koff, kuArr, Wd, y);
    ninja_gemv0<<<dim3(M_ROWS / 64), 512, 0, stream>>>(xT, mask, W, bias, y);
}

// Round 5
// 880.206 us; speedup vs baseline: 3.1648x; 1.0087x over previous
//
#include <hip/hip_runtime.h>
#include <hip/hip_bf16.h>

#define M_ROWS 16384
#define K_IN   2048
#define N_OUT  8192
#define OG     12            // outputs per structural group (identical k-list within group)
#define NG     683           // ceil(8192/12)
#define KUMAX  64            // capacity of per-group k-list (actual ~32 after o=0 exclusion)
#define GPB    4             // groups per main block
#define OTW    (OG*GPB)      // 48 output cols per block = 3 full 64B lines
#define YPAD   52            // ytile row stride: 13 float4 (odd) -> conflict-light b128
#define NTO    171           // ceil(683/4)
#define MT     512           // m rows per main block (2 per thread, adjacent)
#define MAXOFF ((K_IN - 1) * (M_ROWS * 2))   // largest valid xT byte offset (row start)

// ---------------- transpose: x[M][K] f32 -> xT[K][M] bf16 (vectorized) ----------------
// 64(m) x 64(k) tile per block. float4 global reads, k-major LDS tile (pad 66 -> free
// 2-way bank aliasing, 8B-aligned rows for b64 reads), ushort4 bf16 stores (8 B/lane).
__global__ __launch_bounds__(256)
void ninja_xpose(const float* __restrict__ x, __hip_bfloat16* __restrict__ xT) {
    __shared__ float tile[64][66];            // [k][m], pad 66
    int mt = blockIdx.x, kt = blockIdx.y;
    int t = threadIdx.x;
    int r  = t >> 4;          // 0..15  (m-local row for load phase)
    int c4 = (t & 15) * 4;    // k-local col group
#pragma unroll
    for (int p = 0; p < 4; p++) {
        int ro = r + p * 16;  // m-local 0..63
        float4 v = *reinterpret_cast<const float4*>(
            &x[(size_t)(mt * 64 + ro) * K_IN + kt * 64 + c4]);
        tile[c4 + 0][ro] = v.x;
        tile[c4 + 1][ro] = v.y;
        tile[c4 + 2][ro] = v.z;
        tile[c4 + 3][ro] = v.w;
    }
    __syncthreads();
    int kloc = t >> 4;        // 0..15 (k-local row for store phase)
    int m4   = (t & 15) * 4;  // m-local col group
#pragma unroll
    for (int p = 0; p < 4; p++) {
        int ko = kloc + p * 16;   // k-local 0..63
        float f0 = tile[ko][m4 + 0];
        float f1 = tile[ko][m4 + 1];
        float f2 = tile[ko][m4 + 2];
        float f3 = tile[ko][m4 + 3];
        ushort4 u;
        u.x = __hip_bfloat16_raw(__float2bfloat16(f0)).x;
        u.y = __hip_bfloat16_raw(__float2bfloat16(f1)).x;
        u.z = __hip_bfloat16_raw(__float2bfloat16(f2)).x;
        u.w = __hip_bfloat16_raw(__float2bfloat16(f3)).x;
        *reinterpret_cast<ushort4*>(
            &xT[(size_t)(kt * 64 + ko) * M_ROWS + mt * 64 + m4]) = u;
    }
}

// ---------------- prep: per-group k-list (byte offsets) + dense weight panel ----------------
// Output 0 (the only dense output) is EXCLUDED here; its column is produced by ninja_gemv0.
__global__ void ninja_prep(const float* __restrict__ mask, const float* __restrict__ W,
                           int* __restrict__ koff, int* __restrict__ kuArr,
                           float* __restrict__ Wd) {
    int g = blockIdx.x, t = threadIdx.x;
    int o0 = g * OG;
    int no = min(OG, N_OUT - o0);
    __shared__ int cnt;
    __shared__ int kl[KUMAX];
    if (t == 0) cnt = 0;
    __syncthreads();
    for (int k = t; k < K_IN; k += 256) {
        int any = 0;
        for (int oo = 0; oo < no; oo++) {
            int o = o0 + oo;
            any |= (o != 0) & (mask[(size_t)o * K_IN + k] != 0.0f);
        }
        if (any) {
            int p = atomicAdd(&cnt, 1);
            if (p < KUMAX) kl[p] = k;
        }
    }
    __syncthreads();
    int c = cnt;
    if (c > KUMAX) {                  // never expected for this mask; cold safety path
        if (t == 0) kuArr[g] = -1;
        return;
    }
    int kup = (c + 3) & ~3;
    for (int j = c + t; j < kup; j += 256) kl[j] = 0;   // pad entries: k=0, zero weight
    __syncthreads();
    if (t == 0) kuArr[g] = kup;
    for (int j = t; j < KUMAX; j += 256)
        koff[g * KUMAX + j] = (j < kup) ? kl[j] * (M_ROWS * 2) : 0;   // byte offset into xT
    for (int idx = t; idx < KUMAX * OG; idx += 256) {   // 768 floats, 3 iters
        int jk = idx / OG, oo = idx - jk * OG;
        float v = 0.0f;
        int o = o0 + oo;
        if (jk < c && oo < no && o != 0) {
            size_t p = (size_t)o * K_IN + kl[jk];
            v = mask[p] * W[p];
        }
        Wd[(size_t)g * (KUMAX * OG) + idx] = v;
    }
}

// ---------------- main: block = 512 m rows (2/thread, adjacent) x 4 groups ----------------
// Weights: uniform float4 loads from global Wd (s_load/K$). X: one aligned 4-B uint load
// per jk yields two adjacent-m bf16, split by bit-ops (exact bf16->f32).
__global__ __launch_bounds__(256)
void ninja_main(const __hip_bfloat16* __restrict__ xT,
                const float* __restrict__ mask, const float* __restrict__ W,
                const float* __restrict__ bias,
                const int* __restrict__ koff, const int* __restrict__ kuArr,
                const float* __restrict__ Wd, float* __restrict__ y) {
    __shared__ __align__(16) int koffS[GPB][KUMAX];         // 1 KB
    __shared__ int   kusS[GPB];
    __shared__ float biasS[OTW];
    __shared__ __align__(16) float ytile[64][YPAD];         // 13 KB

    int t = threadIdx.x;
    int og0 = blockIdx.x * GPB;
    int o0  = og0 * OG;

    { // stage k-offset lists (coalesced), defensively clamped to valid xT range
        int g = t >> 6, j = t & 63;
        int gg = og0 + g;
        int v = (gg < NG) ? koff[gg * KUMAX + j] : 0;
        koffS[g][j] = min(max(v, 0), MAXOFF);
    }
    if (t < GPB) kusS[t] = (og0 + t < NG) ? kuArr[og0 + t] : 0;
    if (t < OTW) biasS[t] = (o0 + t < N_OUT) ? bias[o0 + t] : 0.0f;
    __syncthreads();

    int m0 = blockIdx.y * MT + 2 * t;                 // this thread: rows m0, m0+1
    const char* xb = reinterpret_cast<const char*>(xT) + 2 * (size_t)m0;

    float accA[GPB][OG], accB[GPB][OG];
#pragma unroll
    for (int g = 0; g < GPB; g++)
#pragma unroll
        for (int oo = 0; oo < OG; oo++) { accA[g][oo] = 0.0f; accB[g][oo] = 0.0f; }

#pragma unroll
    for (int g = 0; g < GPB; g++) {
        int gg = og0 + g;
        int ku = min(kusS[g], KUMAX);
        // block-uniform panel base -> uniform indices below -> scalar loads
        const float4* wp = reinterpret_cast<const float4*>(
            Wd + (size_t)min(gg, NG - 1) * (KUMAX * OG));
        if (ku >= 0) {
            for (int jk = 0; jk < ku; jk += 4) {     // ku is padded to a multiple of 4
                int4 ko = *reinterpret_cast<const int4*>(&koffS[g][jk]);  // uniform b128
#pragma unroll
                for (int u = 0; u < 4; u++) {
                    int off = (u == 0) ? ko.x : (u == 1) ? ko.y : (u == 2) ? ko.z : ko.w;
                    unsigned int xv = *reinterpret_cast<const unsigned int*>(xb + off);
                    float xa = __uint_as_float(xv << 16);           // bf16 at m0
                    float xc = __uint_as_float(xv & 0xffff0000u);   // bf16 at m0+1
                    float4 w0 = wp[(jk + u) * 3 + 0];   // uniform -> s_load_dwordx4
                    float4 w1 = wp[(jk + u) * 3 + 1];
                    float4 w2 = wp[(jk + u) * 3 + 2];
                    accA[g][0]  = fmaf(xa, w0.x, accA[g][0]);  accB[g][0]  = fmaf(xc, w0.x, accB[g][0]);
                    accA[g][1]  = fmaf(xa, w0.y, accA[g][1]);  accB[g][1]  = fmaf(xc, w0.y, accB[g][1]);
                    accA[g][2]  = fmaf(xa, w0.z, accA[g][2]);  accB[g][2]  = fmaf(xc, w0.z, accB[g][2]);
                    accA[g][3]  = fmaf(xa, w0.w, accA[g][3]);  accB[g][3]  = fmaf(xc, w0.w, accB[g][3]);
                    accA[g][4]  = fmaf(xa, w1.x, accA[g][4]);  accB[g][4]  = fmaf(xc, w1.x, accB[g][4]);
                    accA[g][5]  = fmaf(xa, w1.y, accA[g][5]);  accB[g][5]  = fmaf(xc, w1.y, accB[g][5]);
                    accA[g][6]  = fmaf(xa, w1.z, accA[g][6]);  accB[g][6]  = fmaf(xc, w1.z, accB[g][6]);
                    accA[g][7]  = fmaf(xa, w1.w, accA[g][7]);  accB[g][7]  = fmaf(xc, w1.w, accB[g][7]);
                    accA[g][8]  = fmaf(xa, w2.x, accA[g][8]);  accB[g][8]  = fmaf(xc, w2.x, accB[g][8]);
                    accA[g][9]  = fmaf(xa, w2.y, accA[g][9]);  accB[g][9]  = fmaf(xc, w2.y, accB[g][9]);
                    accA[g][10] = fmaf(xa, w2.z, accA[g][10]); accB[g][10] = fmaf(xc, w2.z, accB[g][10]);
                    accA[g][11] = fmaf(xa, w2.w, accA[g][11]); accB[g][11] = fmaf(xc, w2.w, accB[g][11]);
                }
            }
        } else {
            // cold dense safety path (list overflow — not expected for this mask)
            int go0 = gg * OG;
            int no = min(OG, N_OUT - go0);
            for (int k = 0; k < K_IN; k++) {
                unsigned int xv = *reinterpret_cast<const unsigned int*>(xb + k * (M_ROWS * 2));
                float xa = __uint_as_float(xv << 16);
                float xc = __uint_as_float(xv & 0xffff0000u);
#pragma unroll
                for (int oo = 0; oo < OG; oo++) {
                    float wv = 0.f;
                    if (oo < no) {
                        size_t p = (size_t)(go0 + oo) * K_IN + k;
                        wv = mask[p] * W[p];
                    }
                    accA[g][oo] = fmaf(xa, wv, accA[g][oo]);
                    accB[g][oo] = fmaf(xc, wv, accB[g][oo]);
                }
            }
        }
    }

    // ---- coalesced full-line store via LDS transpose, 8 chunks of 64 m-rows ----
    int WID = min(OTW, N_OUT - o0);        // 48 normally, 32 for the last o-tile
    int mbase = blockIdx.y * MT;
#pragma unroll
    for (int cch = 0; cch < 8; cch++) {
        if ((t >> 5) == cch) {             // producing 32 threads: dump 2 rows each
            int r = (t & 31) * 2;
#pragma unroll
            for (int g = 0; g < GPB; g++)
#pragma unroll
                for (int oo = 0; oo < OG; oo++) {
                    float b = biasS[g * OG + oo];
                    ytile[r][g * OG + oo]     = accA[g][oo] + b;
                    ytile[r + 1][g * OG + oo] = accB[g][oo] + b;
                }
        }
        __syncthreads();
        float4* yb = reinterpret_cast<float4*>(y + (size_t)(mbase + cch * 64) * N_OUT + o0);
        if (WID == 48) {
#pragma unroll
            for (int i = 0; i < 3; i++) {
                int idx = t + i * 256;
                int r = idx / 12, q = idx - r * 12;
                float4 v = *reinterpret_cast<const float4*>(&ytile[r][4 * q]);
                yb[(size_t)r * (N_OUT / 4) + q] = v;
            }
        } else {                            // WID == 32
#pragma unroll
            for (int i = 0; i < 2; i++) {
                int idx = t + i * 256;
                int r = idx >> 3, q = idx & 7;
                float4 v = *reinterpret_cast<const float4*>(&ytile[r][4 * q]);
                yb[(size_t)r * (N_OUT / 4) + q] = v;
            }
        }
        __syncthreads();
    }
}

// ---------------- gemv0: dense output column o=0, no atomics ----------------
// Block handles 64 m rows; 8 waves each cover a 256-wide k-slice; LDS reduce; overwrite y[m][0].
__global__ __launch_bounds__(512)
void ninja_gemv0(const __hip_bfloat16* __restrict__ xT,
                 const float* __restrict__ mask, const float* __restrict__ W,
                 const float* __restrict__ bias, float* __restrict__ y) {
    __shared__ float w0[K_IN];      // 8 KB
    __shared__ float part[8][64];
    int t = threadIdx.x;
    for (int k = t; k < K_IN; k += 512) w0[k] = mask[k] * W[k];   // mask row 0 = output 0
    __syncthreads();
    int ml = t & 63;
    int kq = t >> 6;                // wave-uniform k-slice id 0..7
    int m  = blockIdx.x * 64 + ml;
    const __hip_bfloat16* xp = xT + (size_t)(kq * 256) * M_ROWS + m;
    float a = 0.f;
    for (int k = 0; k < 256; k += 8) {
#pragma unroll
        for (int u = 0; u < 8; u++)
            a = fmaf(w0[kq * 256 + k + u],
                     __bfloat162float(xp[(size_t)(k + u) * M_ROWS]), a);
    }
    part[kq][ml] = a;
    __syncthreads();
    if (t < 64) {
        float s = ((part[0][t] + part[1][t]) + (part[2][t] + part[3][t]))
                + ((part[4][t] + part[5][t]) + (part[6][t] + part[7][t]));
        y[(size_t)(blockIdx.x * 64 + t) * N_OUT] = s + bias[0];
    }
}

// ---------------- fallback: plain tiled dense GEMM (used only if ws too small) ----------------
__global__ void ninja_fallback(const float* __restrict__ x, const float* __restrict__ W,
                               const float* __restrict__ bias, const float* __restrict__ mask,
                               float* __restrict__ y) {
    int ot = blockIdx.x, mtile = blockIdx.y, t = threadIdx.x;
    int mloc = t & 63;
    int q = t >> 6;
    int m = mtile * 64 + mloc;
    int obase = ot * 64 + q * 16;
    float acc[16];
#pragma unroll
    for (int i = 0; i < 16; i++) acc[i] = 0.0f;
    __shared__ float xs[32][65];
    for (int kt = 0; kt < K_IN; kt += 32) {
#pragma unroll
        for (int j = 0; j < 8; j++) {
            int idx = t + j * 256;
            int r = idx >> 5, cc = idx & 31;
            xs[cc][r] = x[(size_t)(mtile * 64 + r) * K_IN + kt + cc];
        }
        __syncthreads();
        for (int kk = 0; kk < 32; kk++) {
            float xv = xs[kk][mloc];
#pragma unroll
            for (int i = 0; i < 16; i++) {
                size_t p = (size_t)(obase + i) * K_IN + kt + kk;
                acc[i] = fmaf(xv, mask[p] * W[p], acc[i]);
            }
        }
        __syncthreads();
    }
#pragma unroll
    for (int i = 0; i < 16; i++) acc[i] += bias[obase + i];
    float4* yp = reinterpret_cast<float4*>(y + (size_t)m * N_OUT + obase);
#pragma unroll
    for (int i = 0; i < 4; i++)
        yp[i] = make_float4(acc[4 * i], acc[4 * i + 1], acc[4 * i + 2], acc[4 * i + 3]);
}

extern "C" void kernel_launch(void* const* d_in, const int* in_sizes, int n_in,
                              void* d_out, int out_size, void* d_ws, size_t ws_size,
                              hipStream_t stream) {
    const float* x    = (const float*)d_in[0];
    const float* W    = (const float*)d_in[1];
    const float* bias = (const float*)d_in[2];
    const float* mask = (const float*)d_in[3];
    float* y = (float*)d_out;

    size_t xT_bytes    = (size_t)K_IN * M_ROWS * sizeof(__hip_bfloat16);    // 64 MB
    size_t koff_off    = xT_bytes;
    size_t koff_bytes  = (size_t)NG * KUMAX * sizeof(int);
    size_t ku_off      = koff_off + ((koff_bytes + 255) & ~(size_t)255);
    size_t ku_bytes    = ((size_t)NG * sizeof(int) + 255) & ~(size_t)255;
    size_t wd_off      = ku_off + ku_bytes;
    size_t wd_bytes    = (size_t)NG * KUMAX * OG * sizeof(float);           // ~2.1 MB
    size_t needed      = wd_off + wd_bytes;

    if (ws_size < needed) {
        ninja_fallback<<<dim3(N_OUT / 64, M_ROWS / 64), 256, 0, stream>>>(x, W, bias, mask, y);
        return;
    }

    char* ws = (char*)d_ws;
    __hip_bfloat16* xT = (__hip_bfloat16*)ws;
    int*   koff  = (int*)(ws + koff_off);
    int*   kuArr = (int*)(ws + ku_off);
    float* Wd    = (float*)(ws + wd_off);

    ninja_xpose<<<dim3(M_ROWS / 64, K_IN / 64), 256, 0, stream>>>(x, xT);
    ninja_prep<<<dim3(NG), 256, 0, stream>>>(mask, W, koff, kuArr, Wd);
    ninja_main<<<dim3(NTO, M_ROWS / MT), 256, 0, stream>>>(xT, mask, W, bias, koff, kuArr, Wd, y);
    ninja_gemv0<<<dim3(M_ROWS / 64), 512, 0, stream>>>(xT, mask, W, bias, y);
}